// Round 11
// baseline (126.706 us; speedup 1.0000x reference)
//
#include <hip/hip_runtime.h>
#include <math.h>

// Problem constants (fixed by setup_inputs)
namespace {
constexpr int BS = 16, Q = 900, CN = 91, T = 1600;
constexpr int N  = BS * Q;              // 14400 queries
constexpr float kALPHA = 0.25f;
constexpr float kEPS   = 1e-8f;

constexpr int NT   = 4;                 // n rows per block (R10: 8->4. 3600 blocks
                                        // x 4 waves = 56 waves/CU nominal ->
                                        // saturates the 32/CU cap; R7 showed
                                        // measured occ lags nominal ~2x)
constexpr int BT   = 256;               // threads per block (4 waves)
constexpr int NCOL = T / 4;             // 400 float4 columns over t

typedef float f32x4 __attribute__((ext_vector_type(4)));

// ---------------------------------------------------------------------------
// Fused cost kernel. One block per 4 queries, all 1600 targets per block.
//  - launch_bounds(256,4): 128-VGPR cap; compiler uses 64, no spill.
//    (R9 lesson: (512,8) forced 32 VGPR -> scratch spill -> 180us. Never cap
//    below the live-state footprint.)
//  - focal rows computed from logits exactly once, staged in LDS (1.5 KB)
//  - nontemporal stores: write-once output bypasses L2 so the 32KB t-data
//    stays resident (R7: FETCH=44MB was t-data evicted by the write stream)
// ---------------------------------------------------------------------------
__global__ __launch_bounds__(BT, 4) void k_cost(
    const float*  __restrict__ logits,   // [N*CN]
    const float4* __restrict__ pboxes,   // [N] raw cxcywh
    const float4* __restrict__ tboxes,   // [T] raw cxcywh
    const int*    __restrict__ tlab,     // [T]
    float*        __restrict__ out)      // [N*T]
{
    __shared__ float sK[NT * CN];        // 1.5 KB focal rows for n0..n0+3

    const int tid = threadIdx.x;
    const int n0  = blockIdx.x * NT;

    // ---- stage focal class-cost rows: K[n][c] = pos - neg (once/logit) ----
    for (int i = tid; i < NT * CN; i += BT) {
        float x  = __builtin_nontemporal_load(logits + n0 * CN + i);
        float p  = 1.0f / (1.0f + expf(-x));
        float om = 1.0f - p;
        sK[i] = kALPHA          * om * om * (-logf(p  + kEPS))
              - (1.0f - kALPHA) * p  * p  * (-logf(om + kEPS));
    }

    // ---- per-thread t-state: col0 = tid, col1 = tid+256 (tid < 144) -------
    const int ncol_th = (tid < NCOL - BT) ? 2 : 1;
    float tcx[2][4], tcy[2][4], tww[2][4], thh[2][4], tar[2][4];
    int   tl [2][4];
    #pragma unroll
    for (int j = 0; j < 2; ++j) {
        if (j < ncol_th) {
            const int c = tid + j * BT;
            const int4 lab = *reinterpret_cast<const int4*>(tlab + 4 * c);
            tl[j][0] = lab.x; tl[j][1] = lab.y; tl[j][2] = lab.z; tl[j][3] = lab.w;
            #pragma unroll
            for (int k = 0; k < 4; ++k) {
                const float4 b = tboxes[4 * c + k];
                tcx[j][k] = b.x; tcy[j][k] = b.y; tww[j][k] = b.z; thh[j][k] = b.w;
                const float x0 = b.x - 0.5f * b.z, y0 = b.y - 0.5f * b.w;
                const float x1 = b.x + 0.5f * b.z, y1 = b.y + 0.5f * b.w;
                tar[j][k] = (x1 - x0) * (y1 - y0);   // area from xyxy (match ref)
            }
        }
    }
    __syncthreads();

    #pragma unroll
    for (int i = 0; i < NT; ++i) {
        const int n = n0 + i;
        const float4 braw = pboxes[n];               // wave-uniform
        const float bx0 = braw.x - 0.5f * braw.z, by0 = braw.y - 0.5f * braw.w;
        const float bx1 = braw.x + 0.5f * braw.z, by1 = braw.y + 0.5f * braw.w;
        const float aA  = (bx1 - bx0) * (by1 - by0);
        float* orow = out + (size_t)n * T;

        #pragma unroll
        for (int j = 0; j < 2; ++j) {
            if (j < ncol_th) {
                f32x4 r;
                #pragma unroll
                for (int k = 0; k < 4; ++k) {
                    const float cx = tcx[j][k], cy = tcy[j][k];
                    const float w  = tww[j][k], h  = thh[j][k];
                    const float x0 = cx - 0.5f * w, y0 = cy - 0.5f * h;
                    const float x1 = cx + 0.5f * w, y1 = cy + 0.5f * h;

                    // L1 over raw cxcywh
                    float l1 = fabsf(braw.x - cx) + fabsf(braw.y - cy)
                             + fabsf(braw.z - w ) + fabsf(braw.w - h );

                    // intersection / union
                    float ix0 = fmaxf(bx0, x0), iy0 = fmaxf(by0, y0);
                    float ix1 = fminf(bx1, x1), iy1 = fminf(by1, y1);
                    float inter = fmaxf(ix1 - ix0, 0.0f) * fmaxf(iy1 - iy0, 0.0f);
                    float uni   = aA + tar[j][k] - inter;

                    // enclosing box (rb_c-lt_c >= 0 always; ref's clip is no-op)
                    float cx0 = fminf(bx0, x0), cy0 = fminf(by0, y0);
                    float cx1 = fmaxf(bx1, x1), cy1 = fmaxf(by1, y1);
                    float aC  = (cx1 - cx0) * (cy1 - cy0);

                    const float cls = sK[i * CN + tl[j][k]];

                    // cost = l1 + cls + 1 - inter/uni - uni/aC  (v_rcp_f32)
                    r[k] = l1 + cls + 1.0f
                         - inter * __builtin_amdgcn_rcpf(uni)
                         - uni   * __builtin_amdgcn_rcpf(aC);
                }
                __builtin_nontemporal_store(
                    r, reinterpret_cast<f32x4*>(orow + 4 * (tid + j * BT)));
            }
        }
    }
}
} // namespace

extern "C" void kernel_launch(void* const* d_in, const int* in_sizes, int n_in,
                              void* d_out, int out_size, void* d_ws, size_t ws_size,
                              hipStream_t stream)
{
    const float*  logits = (const float*) d_in[0];   // [16,900,91]
    const float4* pboxes = (const float4*)d_in[1];   // [16,900,4]
    const int*    tlab   = (const int*)   d_in[2];   // [1600]
    const float4* tboxes = (const float4*)d_in[3];   // [1600,4]
    float*        out    = (float*)d_out;            // [16,900,1600]

    hipLaunchKernelGGL(k_cost, dim3(N / NT), dim3(BT), 0, stream,
                       logits, pboxes, tboxes, tlab, out);
}

// Round 12
// 123.824 us; speedup vs baseline: 1.0233x; 1.0233x over previous
//
#include <hip/hip_runtime.h>
#include <math.h>

// Problem constants (fixed by setup_inputs)
namespace {
constexpr int BS = 16, Q = 900, CN = 91, T = 1600;
constexpr int N  = BS * Q;              // 14400 queries
constexpr float kALPHA = 0.25f;
constexpr float kEPS   = 1e-8f;

constexpr int NT   = 4;                 // n rows per block (R10/R11: occupancy
                                        // saturated here; NT=4 == NT=8 perf)
constexpr int BT   = 256;               // threads per block (4 waves)
constexpr int NCOL = T / 4;             // 400 float4 columns over t

typedef float f32x4 __attribute__((ext_vector_type(4)));

// ---------------------------------------------------------------------------
// Fused cost kernel. One block per 4 queries, all 1600 targets per block.
//  - launch_bounds(256,4): 128-VGPR cap; compiler uses 64, no spill.
//    (R9 lesson: (512,8) forced 32 VGPR -> scratch spill -> 180us.)
//  - focal rows computed from logits exactly once, staged in LDS (1.5 KB)
//  - R12 experiment: REGULAR stores (nt removed). R10==R11 proved t-rereads
//    are L3-absorbed (L2-thrash motivation for nt refuted); fills prove the
//    L2-writeback store path sustains 6.2 TB/s, nt path unproven -> isolate it.
// ---------------------------------------------------------------------------
__global__ __launch_bounds__(BT, 4) void k_cost(
    const float*  __restrict__ logits,   // [N*CN]
    const float4* __restrict__ pboxes,   // [N] raw cxcywh
    const float4* __restrict__ tboxes,   // [T] raw cxcywh
    const int*    __restrict__ tlab,     // [T]
    float*        __restrict__ out)      // [N*T]
{
    __shared__ float sK[NT * CN];        // 1.5 KB focal rows for n0..n0+3

    const int tid = threadIdx.x;
    const int n0  = blockIdx.x * NT;

    // ---- stage focal class-cost rows: K[n][c] = pos - neg (once/logit) ----
    for (int i = tid; i < NT * CN; i += BT) {
        float x  = __builtin_nontemporal_load(logits + n0 * CN + i);
        float p  = 1.0f / (1.0f + expf(-x));
        float om = 1.0f - p;
        sK[i] = kALPHA          * om * om * (-logf(p  + kEPS))
              - (1.0f - kALPHA) * p  * p  * (-logf(om + kEPS));
    }

    // ---- per-thread t-state: col0 = tid, col1 = tid+256 (tid < 144) -------
    const int ncol_th = (tid < NCOL - BT) ? 2 : 1;
    float tcx[2][4], tcy[2][4], tww[2][4], thh[2][4], tar[2][4];
    int   tl [2][4];
    #pragma unroll
    for (int j = 0; j < 2; ++j) {
        if (j < ncol_th) {
            const int c = tid + j * BT;
            const int4 lab = *reinterpret_cast<const int4*>(tlab + 4 * c);
            tl[j][0] = lab.x; tl[j][1] = lab.y; tl[j][2] = lab.z; tl[j][3] = lab.w;
            #pragma unroll
            for (int k = 0; k < 4; ++k) {
                const float4 b = tboxes[4 * c + k];
                tcx[j][k] = b.x; tcy[j][k] = b.y; tww[j][k] = b.z; thh[j][k] = b.w;
                const float x0 = b.x - 0.5f * b.z, y0 = b.y - 0.5f * b.w;
                const float x1 = b.x + 0.5f * b.z, y1 = b.y + 0.5f * b.w;
                tar[j][k] = (x1 - x0) * (y1 - y0);   // area from xyxy (match ref)
            }
        }
    }
    __syncthreads();

    #pragma unroll
    for (int i = 0; i < NT; ++i) {
        const int n = n0 + i;
        const float4 braw = pboxes[n];               // wave-uniform
        const float bx0 = braw.x - 0.5f * braw.z, by0 = braw.y - 0.5f * braw.w;
        const float bx1 = braw.x + 0.5f * braw.z, by1 = braw.y + 0.5f * braw.w;
        const float aA  = (bx1 - bx0) * (by1 - by0);
        float* orow = out + (size_t)n * T;

        #pragma unroll
        for (int j = 0; j < 2; ++j) {
            if (j < ncol_th) {
                f32x4 r;
                #pragma unroll
                for (int k = 0; k < 4; ++k) {
                    const float cx = tcx[j][k], cy = tcy[j][k];
                    const float w  = tww[j][k], h  = thh[j][k];
                    const float x0 = cx - 0.5f * w, y0 = cy - 0.5f * h;
                    const float x1 = cx + 0.5f * w, y1 = cy + 0.5f * h;

                    // L1 over raw cxcywh
                    float l1 = fabsf(braw.x - cx) + fabsf(braw.y - cy)
                             + fabsf(braw.z - w ) + fabsf(braw.w - h );

                    // intersection / union
                    float ix0 = fmaxf(bx0, x0), iy0 = fmaxf(by0, y0);
                    float ix1 = fminf(bx1, x1), iy1 = fminf(by1, y1);
                    float inter = fmaxf(ix1 - ix0, 0.0f) * fmaxf(iy1 - iy0, 0.0f);
                    float uni   = aA + tar[j][k] - inter;

                    // enclosing box (rb_c-lt_c >= 0 always; ref's clip is no-op)
                    float cx0 = fminf(bx0, x0), cy0 = fminf(by0, y0);
                    float cx1 = fmaxf(bx1, x1), cy1 = fmaxf(by1, y1);
                    float aC  = (cx1 - cx0) * (cy1 - cy0);

                    const float cls = sK[i * CN + tl[j][k]];

                    // cost = l1 + cls + 1 - inter/uni - uni/aC  (v_rcp_f32)
                    r[k] = l1 + cls + 1.0f
                         - inter * __builtin_amdgcn_rcpf(uni)
                         - uni   * __builtin_amdgcn_rcpf(aC);
                }
                *reinterpret_cast<f32x4*>(orow + 4 * (tid + j * BT)) = r;
            }
        }
    }
}
} // namespace

extern "C" void kernel_launch(void* const* d_in, const int* in_sizes, int n_in,
                              void* d_out, int out_size, void* d_ws, size_t ws_size,
                              hipStream_t stream)
{
    const float*  logits = (const float*) d_in[0];   // [16,900,91]
    const float4* pboxes = (const float4*)d_in[1];   // [16,900,4]
    const int*    tlab   = (const int*)   d_in[2];   // [1600]
    const float4* tboxes = (const float4*)d_in[3];   // [1600,4]
    float*        out    = (float*)d_out;            // [16,900,1600]

    hipLaunchKernelGGL(k_cost, dim3(N / NT), dim3(BT), 0, stream,
                       logits, pboxes, tboxes, tlab, out);
}